// Round 2
// baseline (769.773 us; speedup 1.0000x reference)
//
#include <hip/hip_runtime.h>
#include <math.h>

typedef unsigned int uint;
typedef unsigned short ushort;

// ---------- helpers ----------
__device__ __forceinline__ float b2f(ushort u){
  union { uint i; float f; } v; v.i = ((uint)u) << 16; return v.f;
}
__device__ __forceinline__ ushort f2b(float f){
  union { float f; uint i; } v; v.f = f;
  uint i = v.i;
  i += 0x7fffu + ((i >> 16) & 1u);   // RNE
  return (ushort)(i >> 16);
}
__device__ __forceinline__ float wred(float v){
  #pragma unroll
  for (int s = 32; s > 0; s >>= 1) v += __shfl_xor(v, s, 64);
  return v;
}
__device__ __forceinline__ float sane(float v){ return isfinite(v) ? v : 0.f; }
__device__ __forceinline__ int iclamp(int v, int lo, int hi){ return v < lo ? lo : (v > hi ? hi : v); }

// B=1024, L=200, H=128, HEADS=8, D=16, N_NODE=200000, MAXN=201
#define OUTB 131072

// canonical f32 weight layout (float offsets inside ws_wts)
#define C_W0T 0        // 128x128, W0T[k*128+h] = W0[h,k]
#define C_W1  16384    // 128x128 as-is
#define C_W2T 32768    // transposed
#define C_WQT 49152    // transposed
#define C_WTT 65536    // 256x128, WtT[k*128+h] = Wt[h,k]
#define C_B0  98304
#define C_B1  98432
#define C_B2  98560
#define C_BQ  98688
#define C_BT  98816
#define C_G   98944
#define C_BB  99072
#define C_TOT 99200

// ---------- dtype detector: f32 data read as bf16 has huge/NaN values ----------
__global__ __launch_bounds__(256) void k_detect(const ushort* __restrict__ emb,
                                                int* __restrict__ flag){
  __shared__ int s_bad;
  if (threadIdx.x == 0) s_bad = 0;
  __syncthreads();
  int bad = 0;
  for (int i = threadIdx.x; i < 8192; i += 256){
    float v = fabsf(b2f(emb[i]));
    if (!(v <= 1e4f)) bad = 1;    // catches >1e4 and NaN patterns
  }
  if (bad) s_bad = 1;
  __syncthreads();
  if (threadIdx.x == 0) flag[0] = s_bad;   // 1 = inputs are f32, 0 = bf16
}

// ---------- convert all small weights to canonical f32 (pre-transposed) ----------
__global__ __launch_bounds__(256) void k_wts(
    const void* W0, const void* b0, const void* W1, const void* b1,
    const void* W2, const void* b2, const void* Wq, const void* bq,
    const void* Wt, const void* bt, const void* g, const void* bb,
    const int* __restrict__ flag, float* __restrict__ wts){
  int j = blockIdx.x * 256 + threadIdx.x;
  if (j >= C_TOT) return;
  const int isf = flag[0];
  const void* src; int si;
  if (j < 16384)      { int k = j >> 7, h = j & 127; src = W0; si = h * 128 + k; }
  else if (j < 32768) { src = W1; si = j - 16384; }
  else if (j < 49152) { int i = j - 32768; int k = i >> 7, h = i & 127; src = W2; si = h * 128 + k; }
  else if (j < 65536) { int i = j - 49152; int k = i >> 7, h = i & 127; src = Wq; si = h * 128 + k; }
  else if (j < 98304) { int i = j - 65536; int k = i >> 7, h = i & 127; src = Wt; si = h * 256 + k; }
  else {
    int i = j - 98304; int arr = i >> 7;
    const void* tab[7] = { b0, b1, b2, bq, bt, g, bb };
    src = tab[arr]; si = i & 127;
  }
  wts[j] = isf ? ((const float*)src)[si] : b2f(((const ushort*)src)[si]);
}

// ---------- b output: normalize(emb_W[1:]) transposed ----------
__global__ __launch_bounds__(256) void k_bout(const void* __restrict__ emb,
                                              const int* __restrict__ flag,
                                              void* __restrict__ outv){
  __shared__ float tile[64 * 129];
  const int t = threadIdx.x, wv = t >> 6, lane = t & 63;
  const int base = blockIdx.x * 64;
  const int isf = flag[0];
  for (int i = wv; i < 64; i += 4){
    int gi = base + i;
    if (gi < 199999){
      float x0, x1;
      if (isf){ float2 u = ((const float2*)emb)[(size_t)(gi + 1) * 64 + lane]; x0 = u.x; x1 = u.y; }
      else    { uint u = ((const uint*)emb)[(size_t)(gi + 1) * 64 + lane];
                x0 = b2f((ushort)u); x1 = b2f((ushort)(u >> 16)); }
      float ss = wred(x0 * x0 + x1 * x1);
      float inv = 1.f / (sqrtf(ss) + 1e-12f);
      tile[i * 129 + lane * 2]     = x0 * inv;
      tile[i * 129 + lane * 2 + 1] = x1 * inv;
    }
  }
  __syncthreads();
  for (int it = 0; it < 32; ++it){
    int idx = it * 256 + t;
    int h = idx >> 6, n = idx & 63;
    int gi = base + n;
    if (gi < 199999){
      float val = sane(tile[n * 129 + h]);
      if (isf) ((float*)outv)[OUTB + (size_t)h * 199999 + gi] = val;
      else     ((ushort*)outv)[OUTB + (size_t)h * 199999 + gi] = f2b(val);
    }
  }
}

// ---------- per-batch prep: len, ht_last, hts(sign,f64), X0, c1 ----------
__global__ __launch_bounds__(128) void k_prep(
    const int* __restrict__ alias_, const int* __restrict__ items,
    const int* __restrict__ mask, const void* __restrict__ emb,
    const float* __restrict__ wts, const int* __restrict__ flag,
    float* __restrict__ ws_ht, float* __restrict__ ws_X0,
    float* __restrict__ ws_c1, int* __restrict__ ws_len){
  __shared__ float s_ht[128], s_hts[128], s_X0s[128];
  __shared__ float s_red[8];
  __shared__ int s_item;
  const int b = blockIdx.x, t = threadIdx.x, w = t >> 6;
  const int isf = flag[0];

  int mv = mask[b * 200 + t] + (t < 72 ? mask[b * 200 + 128 + t] : 0);
  float lv = wred((float)mv);
  if ((t & 63) == 0) s_red[w] = lv;
  __syncthreads();
  int len = iclamp((int)(s_red[0] + s_red[1] + 0.5f), 1, 200);
  if (t == 0){
    ws_len[b] = len;
    int a = iclamp(alias_[b * 200 + len - 1], 0, 200);
    s_item = iclamp(items[b * 201 + a], 0, 199999);
  }
  __syncthreads();

  float v = isf ? ((const float*)emb)[(size_t)s_item * 128 + t]
                : b2f(((const ushort*)emb)[(size_t)s_item * 128 + t]);
  float ss = wred(v * v);
  if ((t & 63) == 0) s_red[2 + w] = ss;
  __syncthreads();
  v = v / (sqrtf(s_red[2] + s_red[3]) + 1e-12f);
  float ss2 = wred(v * v);
  if ((t & 63) == 0) s_red[4 + w] = ss2;
  __syncthreads();
  v = v / (sqrtf(s_red[4] + s_red[5]) + 1e-12f);
  s_ht[t] = v;
  ws_ht[b * 128 + t] = v;
  __syncthreads();

  // hts = x/(|x|+eps): sign-like, f64 accumulate to match the high-precision ref
  {
    double acc = (double)wts[C_BQ + t];
    for (int k = 0; k < 128; ++k)
      acc += (double)wts[C_WQT + k * 128 + t] * (double)s_ht[k];
    float a = (float)acc;
    s_hts[t] = a / (fabsf(a) + 1e-12f);
  }
  __syncthreads();
  {
    float a0 = wts[C_B0 + t];
    for (int k = 0; k < 128; ++k) a0 += wts[C_W0T + k * 128 + t] * s_hts[k];
    s_X0s[t] = a0;
    ws_X0[b * 128 + t] = a0;
  }
  __syncthreads();
  if (t < 64){
    int head = t >> 3, j = t & 7;
    float c = 0.f;
    #pragma unroll
    for (int d = 0; d < 16; ++d) c += s_X0s[head * 16 + d] * wts[C_B1 + j * 16 + d];
    ws_c1[b * 64 + t] = c;
  }
}

// ---------- per-batch main: logits -> softmax -> head sums -> LN -> out ----------
__global__ __launch_bounds__(256) void k_main(
    const int* __restrict__ alias_, const int* __restrict__ items,
    const int* __restrict__ mask, const void* __restrict__ emb,
    const float* __restrict__ wts, const float* __restrict__ ws_ht,
    const float* __restrict__ ws_X0, const float* __restrict__ ws_c1,
    const int* __restrict__ ws_len, const int* __restrict__ flag,
    void* __restrict__ outv){
  __shared__ float s_alpha[1600];
  __shared__ float s_w1p[64 * 130];
  __shared__ float s_part[4096];       // wave partials, then s_hl[8][128] in [0,1024)
  __shared__ float s_X0[128], s_ht[128], s_a[128];
  __shared__ float s_c1[64];
  __shared__ float s_T[8], s_Tp[32];
  __shared__ float s_red[16];

  const int b = blockIdx.x, t = threadIdx.x;
  const int wv = t >> 6, lane = t & 63;
  const int isf = flag[0];
  const int len = iclamp(ws_len[b], 1, 200);

  if (t < 128){ s_X0[t] = ws_X0[b * 128 + t]; s_ht[t] = ws_ht[b * 128 + t]; }
  if (t < 64)  s_c1[t] = ws_c1[b * 64 + t];
  __syncthreads();

  // W1p[head,j,k] = sum_d X0[head*16+d] * W1[j*16+d, k]   (LDS, padded stride 130)
  for (int idx = t; idx < 8192; idx += 256){
    int hj = idx >> 7, k = idx & 127, head = hj >> 3, j = hj & 7;
    float acc = 0.f;
    const float* w1r = wts + C_W1 + (j * 16) * 128 + k;
    #pragma unroll
    for (int d = 0; d < 16; ++d) acc += s_X0[head * 16 + d] * w1r[d * 128];
    s_w1p[hj * 130 + k] = acc;
  }
  __syncthreads();

  // phase b: per row r, gather+normalize in registers, 8 logits via wave reductions
  for (int r = wv; r < 200; r += 4){
    int m = mask[b * 200 + r];
    float x0 = 0.f, x1 = 0.f;
    if (m){
      int a = iclamp(alias_[b * 200 + r], 0, 200);
      int it = iclamp(items[b * 201 + a], 0, 199999);
      if (isf){ float2 u = ((const float2*)emb)[(size_t)it * 64 + lane]; x0 = u.x; x1 = u.y; }
      else    { uint u = ((const uint*)emb)[(size_t)it * 64 + lane];
                x0 = b2f((ushort)u); x1 = b2f((ushort)(u >> 16)); }
      float ss = wred(x0 * x0 + x1 * x1);
      float inv = 1.f / (sqrtf(ss) + 1e-12f);
      x0 *= inv; x1 *= inv;
      float ss2 = wred(x0 * x0 + x1 * x1);
      float inv2 = 1.f / (sqrtf(ss2) + 1e-12f);
      x0 *= inv2; x1 *= inv2;
    }
    int head = r / 25, lb = (r % 25) * 8;    // seq row r -> (head, l=lb+j) logits
    for (int j = 0; j < 8; ++j){
      float2 wv2 = *(const float2*)&s_w1p[(head * 8 + j) * 130 + lane * 2];
      float dot = wred(x0 * wv2.x + x1 * wv2.y);
      if (lane == 0){
        float logit = s_c1[head * 8 + j] + dot;
        s_alpha[(lb + j) * 8 + head] = 2.f / (1.f + expf(-logit));
      }
    }
  }
  __syncthreads();

  // phase c: softmax over l (all 200 positions) per head
  {
    int head = t >> 5, l32 = t & 31;
    float vals[7]; float mx = -1e30f;
    #pragma unroll
    for (int i = 0; i < 7; ++i){
      int l = l32 + 32 * i;
      float x = (l < 200) ? s_alpha[l * 8 + head] : -1e30f;
      vals[i] = x; mx = fmaxf(mx, x);
    }
    #pragma unroll
    for (int s = 16; s > 0; s >>= 1) mx = fmaxf(mx, __shfl_xor(mx, s, 64));
    float sum = 0.f; float e[7];
    #pragma unroll
    for (int i = 0; i < 7; ++i){
      int l = l32 + 32 * i;
      float ex = (l < 200) ? expf(vals[i] - mx) : 0.f;
      e[i] = ex; sum += ex;
    }
    #pragma unroll
    for (int s = 16; s > 0; s >>= 1) sum += __shfl_xor(sum, s, 64);
    float inv = 1.f / sum;
    #pragma unroll
    for (int i = 0; i < 7; ++i){
      int l = l32 + 32 * i;
      if (l < 200) s_alpha[l * 8 + head] = e[i] * inv;
    }
  }
  __syncthreads();

  // phase d: re-gather rows (L3-hot), accumulate alpha-weighted head sums + T
  float ax[8] = {0,0,0,0,0,0,0,0}, ay[8] = {0,0,0,0,0,0,0,0}, ts[8] = {0,0,0,0,0,0,0,0};
  for (int r = wv; r < 200; r += 4){
    int m = mask[b * 200 + r];
    if (m){
      int a = iclamp(alias_[b * 200 + r], 0, 200);
      int it = iclamp(items[b * 201 + a], 0, 199999);
      float x0, x1;
      if (isf){ float2 u = ((const float2*)emb)[(size_t)it * 64 + lane]; x0 = u.x; x1 = u.y; }
      else    { uint u = ((const uint*)emb)[(size_t)it * 64 + lane];
                x0 = b2f((ushort)u); x1 = b2f((ushort)(u >> 16)); }
      float ss = wred(x0 * x0 + x1 * x1);
      float inv = 1.f / (sqrtf(ss) + 1e-12f);
      x0 *= inv; x1 *= inv;
      float ss2 = wred(x0 * x0 + x1 * x1);
      float inv2 = 1.f / (sqrtf(ss2) + 1e-12f);
      x0 *= inv2; x1 *= inv2;
      #pragma unroll
      for (int h2 = 0; h2 < 8; ++h2){
        float aw = s_alpha[r * 8 + h2];
        ax[h2] += aw * x0; ay[h2] += aw * x1; ts[h2] += aw;
      }
    }
  }
  #pragma unroll
  for (int h2 = 0; h2 < 8; ++h2){
    s_part[wv * 1024 + h2 * 128 + lane * 2]     = ax[h2];
    s_part[wv * 1024 + h2 * 128 + lane * 2 + 1] = ay[h2];
  }
  if (lane == 0){
    #pragma unroll
    for (int h2 = 0; h2 < 8; ++h2) s_Tp[wv * 8 + h2] = ts[h2];
  }
  __syncthreads();
  for (int i = t; i < 1024; i += 256){
    float s = s_part[i] + s_part[1024 + i] + s_part[2048 + i] + s_part[3072 + i];
    s_part[i] = s;   // s_hl[head*128+k]
  }
  if (t < 8) s_T[t] = s_Tp[t] + s_Tp[8 + t] + s_Tp[16 + t] + s_Tp[24 + t];
  __syncthreads();

  // phase e: a_raw = s_hl . W2T + T*b2 ; layernorm
  float araw = 0.f;
  if (t < 128){
    int head = t >> 4;
    araw = wts[C_B2 + t] * s_T[head];
    const float* hl = &s_part[head * 128];
    for (int k = 0; k < 128; ++k) araw += hl[k] * wts[C_W2T + k * 128 + t];
  }
  float v1 = wred(t < 128 ? araw : 0.f);
  if ((t & 63) == 0) s_red[t >> 6] = v1;
  __syncthreads();
  float mu = (s_red[0] + s_red[1]) * 0.0078125f;
  float dd = (t < 128) ? (araw - mu) : 0.f;
  float v2 = wred(dd * dd);
  if ((t & 63) == 0) s_red[4 + (t >> 6)] = v2;
  __syncthreads();
  float var = (s_red[4] + s_red[5]) * 0.0078125f;
  if (t < 128)
    s_a[t] = dd / sqrtf(var + 1e-8f) * wts[C_G + t] + wts[C_BB + t];
  __syncthreads();

  // phase f: out = normalize([a_ln | ht] . WtT + bt)
  float o = 0.f;
  if (t < 128){
    o = wts[C_BT + t];
    for (int k = 0; k < 128; ++k) o += s_a[k] * wts[C_WTT + k * 128 + t];
    for (int k = 0; k < 128; ++k) o += s_ht[k] * wts[C_WTT + (128 + k) * 128 + t];
  }
  float v3 = wred(t < 128 ? o * o : 0.f);
  if ((t & 63) == 0) s_red[8 + (t >> 6)] = v3;
  __syncthreads();
  float nrm = sqrtf(s_red[8] + s_red[9]);
  if (t < 128){
    float val = sane(o / (nrm + 1e-12f));
    if (isf) ((float*)outv)[b * 128 + t] = val;
    else     ((ushort*)outv)[b * 128 + t] = f2b(val);
  }
}

extern "C" void kernel_launch(void* const* d_in, const int* in_sizes, int n_in,
                              void* d_out, int out_size, void* d_ws, size_t ws_size,
                              hipStream_t stream){
  const int* alias_ = (const int*)d_in[0];
  const int* items  = (const int*)d_in[1];
  const int* mask   = (const int*)d_in[2];
  const void* emb = d_in[3];
  const void* W0  = d_in[4];
  const void* b0  = d_in[5];
  const void* W1  = d_in[6];
  const void* b1  = d_in[7];
  const void* W2  = d_in[8];
  const void* b2_ = d_in[9];
  const void* Wq  = d_in[10];
  const void* bq  = d_in[11];
  const void* Wt  = d_in[12];
  const void* bt  = d_in[13];
  const void* g_  = d_in[14];
  const void* bb_ = d_in[15];

  char* ws = (char*)d_ws;
  int*   ws_flag = (int*)ws;                  // 64 B
  float* wts     = (float*)(ws + 64);         // 396,800 B
  float* ws_ht   = (float*)(ws + 396864);     // 524,288 B
  float* ws_X0   = (float*)(ws + 921152);     // 524,288 B
  float* ws_c1   = (float*)(ws + 1445440);    // 262,144 B
  int*   ws_len  = (int*)(ws + 1707584);      // 4,096 B  (total ~1.71 MB)

  k_detect<<<dim3(1),    dim3(256), 0, stream>>>((const ushort*)emb, ws_flag);
  k_wts   <<<dim3(388),  dim3(256), 0, stream>>>(W0, b0, W1, b1, W2, b2_, Wq, bq,
                                                 Wt, bt, g_, bb_, ws_flag, wts);
  k_bout  <<<dim3(3125), dim3(256), 0, stream>>>(emb, ws_flag, d_out);
  k_prep  <<<dim3(1024), dim3(128), 0, stream>>>(alias_, items, mask, emb, wts, ws_flag,
                                                 ws_ht, ws_X0, ws_c1, ws_len);
  k_main  <<<dim3(1024), dim3(256), 0, stream>>>(alias_, items, mask, emb, wts,
                                                 ws_ht, ws_X0, ws_c1, ws_len, ws_flag, d_out);
}

// Round 3
// 414.837 us; speedup vs baseline: 1.8556x; 1.8556x over previous
//
#include <hip/hip_runtime.h>
#include <math.h>

typedef unsigned int uint;
typedef unsigned short ushort;

// ---------- helpers ----------
__device__ __forceinline__ float b2f(ushort u){
  union { uint i; float f; } v; v.i = ((uint)u) << 16; return v.f;
}
__device__ __forceinline__ ushort f2b(float f){
  union { float f; uint i; } v; v.f = f;
  uint i = v.i;
  i += 0x7fffu + ((i >> 16) & 1u);   // RNE
  return (ushort)(i >> 16);
}
__device__ __forceinline__ float wred(float v){
  #pragma unroll
  for (int s = 32; s > 0; s >>= 1) v += __shfl_xor(v, s, 64);
  return v;
}
// reduction within 16-lane groups (4-deep chain)
__device__ __forceinline__ float gred16(float v){
  v += __shfl_xor(v, 1, 64);
  v += __shfl_xor(v, 2, 64);
  v += __shfl_xor(v, 4, 64);
  v += __shfl_xor(v, 8, 64);
  return v;
}
__device__ __forceinline__ float sane(float v){ return isfinite(v) ? v : 0.f; }
__device__ __forceinline__ int iclamp(int v, int lo, int hi){ return v < lo ? lo : (v > hi ? hi : v); }

// gather one emb row chunk (8 elems for lane-position p) and double-normalize
// across the 16-lane group. All 16 lanes of a group must be active.
__device__ __forceinline__ void gather_norm8(const void* emb, int isf, int it, int p, float x[8]){
  if (isf){
    const float4* q = (const float4*)((const float*)emb + (size_t)it * 128);
    float4 u = q[p * 2], u2 = q[p * 2 + 1];
    x[0] = u.x; x[1] = u.y; x[2] = u.z; x[3] = u.w;
    x[4] = u2.x; x[5] = u2.y; x[6] = u2.z; x[7] = u2.w;
  } else {
    uint4 u = ((const uint4*)((const ushort*)emb + (size_t)it * 128))[p];
    x[0] = b2f((ushort)u.x); x[1] = b2f((ushort)(u.x >> 16));
    x[2] = b2f((ushort)u.y); x[3] = b2f((ushort)(u.y >> 16));
    x[4] = b2f((ushort)u.z); x[5] = b2f((ushort)(u.z >> 16));
    x[6] = b2f((ushort)u.w); x[7] = b2f((ushort)(u.w >> 16));
  }
  float ss = 0.f;
  #pragma unroll
  for (int e = 0; e < 8; ++e) ss += x[e] * x[e];
  ss = gred16(ss);
  float inv = 1.f / (sqrtf(ss) + 1e-12f);
  #pragma unroll
  for (int e = 0; e < 8; ++e) x[e] *= inv;
  float ss2 = 0.f;
  #pragma unroll
  for (int e = 0; e < 8; ++e) ss2 += x[e] * x[e];
  ss2 = gred16(ss2);
  float inv2 = 1.f / (sqrtf(ss2) + 1e-12f);
  #pragma unroll
  for (int e = 0; e < 8; ++e) x[e] *= inv2;
}

// B=1024, L=200, H=128, HEADS=8, D=16, N_NODE=200000, MAXN=201
#define OUTB 131072

// canonical f32 weight layout (float offsets inside ws_wts)
#define C_W0T 0        // 128x128, W0T[k*128+h] = W0[h,k]
#define C_W1  16384    // 128x128 as-is
#define C_W2T 32768    // transposed
#define C_WQT 49152    // transposed
#define C_WTT 65536    // 256x128, WtT[k*128+h] = Wt[h,k]
#define C_B0  98304
#define C_B1  98432
#define C_B2  98560
#define C_BQ  98688
#define C_BT  98816
#define C_G   98944
#define C_BB  99072
#define C_TOT 99200

// ---------- dtype detector: f32 data read as bf16 has huge/NaN values ----------
__global__ __launch_bounds__(256) void k_detect(const ushort* __restrict__ emb,
                                                int* __restrict__ flag){
  __shared__ int s_bad;
  if (threadIdx.x == 0) s_bad = 0;
  __syncthreads();
  int bad = 0;
  for (int i = threadIdx.x; i < 8192; i += 256){
    float v = fabsf(b2f(emb[i]));
    if (!(v <= 1e4f)) bad = 1;
  }
  if (bad) s_bad = 1;
  __syncthreads();
  if (threadIdx.x == 0) flag[0] = s_bad;   // 1 = inputs are f32, 0 = bf16
}

// ---------- convert all small weights to canonical f32 (pre-transposed) ----------
__global__ __launch_bounds__(256) void k_wts(
    const void* W0, const void* b0, const void* W1, const void* b1,
    const void* W2, const void* b2, const void* Wq, const void* bq,
    const void* Wt, const void* bt, const void* g, const void* bb,
    const int* __restrict__ flag, float* __restrict__ wts){
  int j = blockIdx.x * 256 + threadIdx.x;
  if (j >= C_TOT) return;
  const int isf = flag[0];
  const void* src; int si;
  if (j < 16384)      { int k = j >> 7, h = j & 127; src = W0; si = h * 128 + k; }
  else if (j < 32768) { src = W1; si = j - 16384; }
  else if (j < 49152) { int i = j - 32768; int k = i >> 7, h = i & 127; src = W2; si = h * 128 + k; }
  else if (j < 65536) { int i = j - 49152; int k = i >> 7, h = i & 127; src = Wq; si = h * 128 + k; }
  else if (j < 98304) { int i = j - 65536; int k = i >> 7, h = i & 127; src = Wt; si = h * 256 + k; }
  else {
    int i = j - 98304; int arr = i >> 7;
    const void* tab[7] = { b0, b1, b2, bq, bt, g, bb };
    src = tab[arr]; si = i & 127;
  }
  wts[j] = isf ? ((const float*)src)[si] : b2f(((const ushort*)src)[si]);
}

// ---------- b output: normalize(emb_W[1:]) transposed ----------
__global__ __launch_bounds__(256) void k_bout(const void* __restrict__ emb,
                                              const int* __restrict__ flag,
                                              void* __restrict__ outv){
  __shared__ float tile[64 * 129];
  const int t = threadIdx.x, gid = t >> 4, p = t & 15;
  const int base = blockIdx.x * 64;
  const int isf = flag[0];
  for (int i = gid; i < 64; i += 16){
    int gi = base + i;
    if (gi < 199999){
      float x[8];
      if (isf){
        const float4* q = (const float4*)((const float*)emb + (size_t)(gi + 1) * 128);
        float4 u = q[p * 2], u2 = q[p * 2 + 1];
        x[0] = u.x; x[1] = u.y; x[2] = u.z; x[3] = u.w;
        x[4] = u2.x; x[5] = u2.y; x[6] = u2.z; x[7] = u2.w;
      } else {
        uint4 u = ((const uint4*)((const ushort*)emb + (size_t)(gi + 1) * 128))[p];
        x[0] = b2f((ushort)u.x); x[1] = b2f((ushort)(u.x >> 16));
        x[2] = b2f((ushort)u.y); x[3] = b2f((ushort)(u.y >> 16));
        x[4] = b2f((ushort)u.z); x[5] = b2f((ushort)(u.z >> 16));
        x[6] = b2f((ushort)u.w); x[7] = b2f((ushort)(u.w >> 16));
      }
      float ss = 0.f;
      #pragma unroll
      for (int e = 0; e < 8; ++e) ss += x[e] * x[e];
      ss = gred16(ss);
      float inv = 1.f / (sqrtf(ss) + 1e-12f);
      #pragma unroll
      for (int e = 0; e < 8; ++e) tile[i * 129 + p * 8 + e] = x[e] * inv;
    }
  }
  __syncthreads();
  for (int it = 0; it < 32; ++it){
    int idx = it * 256 + t;
    int h = idx >> 6, n = idx & 63;
    int gi = base + n;
    if (gi < 199999){
      float val = sane(tile[n * 129 + h]);
      if (isf) ((float*)outv)[OUTB + (size_t)h * 199999 + gi] = val;
      else     ((ushort*)outv)[OUTB + (size_t)h * 199999 + gi] = f2b(val);
    }
  }
}

// ---------- per-batch prep: len, ht_last, hts(sign,f64), X0, c1 ----------
__global__ __launch_bounds__(128) void k_prep(
    const int* __restrict__ alias_, const int* __restrict__ items,
    const int* __restrict__ mask, const void* __restrict__ emb,
    const float* __restrict__ wts, const int* __restrict__ flag,
    float* __restrict__ ws_ht, float* __restrict__ ws_X0,
    float* __restrict__ ws_c1, int* __restrict__ ws_len){
  __shared__ float s_ht[128], s_hts[128], s_X0s[128];
  __shared__ float s_red[8];
  __shared__ int s_item;
  const int b = blockIdx.x, t = threadIdx.x, w = t >> 6;
  const int isf = flag[0];

  int mv = mask[b * 200 + t] + (t < 72 ? mask[b * 200 + 128 + t] : 0);
  float lv = wred((float)mv);
  if ((t & 63) == 0) s_red[w] = lv;
  __syncthreads();
  int len = iclamp((int)(s_red[0] + s_red[1] + 0.5f), 1, 200);
  if (t == 0){
    ws_len[b] = len;
    int a = iclamp(alias_[b * 200 + len - 1], 0, 200);
    s_item = iclamp(items[b * 201 + a], 0, 199999);
  }
  __syncthreads();

  float v = isf ? ((const float*)emb)[(size_t)s_item * 128 + t]
                : b2f(((const ushort*)emb)[(size_t)s_item * 128 + t]);
  float ss = wred(v * v);
  if ((t & 63) == 0) s_red[2 + w] = ss;
  __syncthreads();
  v = v / (sqrtf(s_red[2] + s_red[3]) + 1e-12f);
  float ss2 = wred(v * v);
  if ((t & 63) == 0) s_red[4 + w] = ss2;
  __syncthreads();
  v = v / (sqrtf(s_red[4] + s_red[5]) + 1e-12f);
  s_ht[t] = v;
  ws_ht[b * 128 + t] = v;
  __syncthreads();

  // hts = x/(|x|+eps): sign-like, f64 accumulate for stability
  {
    double acc = (double)wts[C_BQ + t];
    for (int k = 0; k < 128; ++k)
      acc += (double)wts[C_WQT + k * 128 + t] * (double)s_ht[k];
    float a = (float)acc;
    s_hts[t] = a / (fabsf(a) + 1e-12f);
  }
  __syncthreads();
  {
    float a0 = wts[C_B0 + t];
    for (int k = 0; k < 128; ++k) a0 += wts[C_W0T + k * 128 + t] * s_hts[k];
    s_X0s[t] = a0;
    ws_X0[b * 128 + t] = a0;
  }
  __syncthreads();
  if (t < 64){
    int head = t >> 3, j = t & 7;
    float c = 0.f;
    #pragma unroll
    for (int d = 0; d < 16; ++d) c += s_X0s[head * 16 + d] * wts[C_B1 + j * 16 + d];
    ws_c1[b * 64 + t] = c;
  }
}

// ---------- per-batch main ----------
__global__ __launch_bounds__(256) void k_main(
    const int* __restrict__ alias_, const int* __restrict__ items,
    const int* __restrict__ mask, const void* __restrict__ emb,
    const float* __restrict__ wts, const float* __restrict__ ws_ht,
    const float* __restrict__ ws_X0, const float* __restrict__ ws_c1,
    const int* __restrict__ ws_len, const int* __restrict__ flag,
    void* __restrict__ outv){
  // region A: bf16 W1p (64 rows x stride 136 shorts = 17,408 B), later reused
  // as f32 head-sum partials s_part[4096] (16,384 B)
  __shared__ __align__(16) char s_buf[17408];
  __shared__ float s_alpha[1600];
  __shared__ float s_X0[128], s_ht[128], s_a[128];
  __shared__ float s_c1[64];
  __shared__ float s_T[8], s_Tp[64];
  __shared__ float s_red[16];
  __shared__ int   s_it[200];     // resolved item index per row (-1 = masked)
  ushort* s_w1p = (ushort*)s_buf;
  float*  s_part = (float*)s_buf;

  const int b = blockIdx.x, t = threadIdx.x;
  const int wv = t >> 6, gid = t >> 4, p = t & 15, lane = t & 63;
  const int isf = flag[0];
  const int len = iclamp(ws_len[b], 1, 200);
  const int mbase = b * 200;

  if (t < 128){ s_X0[t] = ws_X0[b * 128 + t]; s_ht[t] = ws_ht[b * 128 + t]; }
  if (t < 64)  s_c1[t] = ws_c1[b * 64 + t];
  if (t < 200){
    int m = mask[mbase + t];
    int a = m ? iclamp(alias_[mbase + t], 0, 200) : 0;
    s_it[t] = m ? iclamp(items[b * 201 + a], 0, 199999) : -1;
  }
  __syncthreads();

  // W1p[head*8+j][k] = sum_d X0[head*16+d] * W1[j*16+d, k], bf16 in LDS
  for (int idx = t; idx < 8192; idx += 256){
    int hj = idx >> 7, k = idx & 127, head = hj >> 3, j = hj & 7;
    float acc = 0.f;
    const float* w1r = wts + C_W1 + (j * 16) * 128 + k;
    #pragma unroll
    for (int d = 0; d < 16; ++d) acc += s_X0[head * 16 + d] * w1r[d * 128];
    s_w1p[hj * 136 + k] = f2b(acc);
  }
  __syncthreads();

  // phase b: per row (16-lane group), gather+norm in regs, 8 logits per row
  for (int r = gid; r < 200; r += 16){
    int it = s_it[r];
    float x[8];
    #pragma unroll
    for (int e = 0; e < 8; ++e) x[e] = 0.f;
    if (it >= 0) gather_norm8(emb, isf, it, p, x);
    int head = r / 25, lb = (r % 25) * 8;
    #pragma unroll
    for (int j = 0; j < 8; ++j){
      uint4 wu = *(const uint4*)(&s_w1p[(head * 8 + j) * 136 + p * 8]);
      float dot = x[0] * b2f((ushort)wu.x) + x[1] * b2f((ushort)(wu.x >> 16))
                + x[2] * b2f((ushort)wu.y) + x[3] * b2f((ushort)(wu.y >> 16))
                + x[4] * b2f((ushort)wu.z) + x[5] * b2f((ushort)(wu.z >> 16))
                + x[6] * b2f((ushort)wu.w) + x[7] * b2f((ushort)(wu.w >> 16));
      dot = gred16(dot);
      if (p == 0){
        float logit = s_c1[head * 8 + j] + dot;
        s_alpha[(lb + j) * 8 + head] = 2.f / (1.f + expf(-logit));
      }
    }
  }
  __syncthreads();

  // phase c: softmax over all 200 positions per head
  {
    int head = t >> 5, l32 = t & 31;
    float vals[7]; float mx = -1e30f;
    #pragma unroll
    for (int i = 0; i < 7; ++i){
      int l = l32 + 32 * i;
      float xx = (l < 200) ? s_alpha[l * 8 + head] : -1e30f;
      vals[i] = xx; mx = fmaxf(mx, xx);
    }
    #pragma unroll
    for (int s = 16; s > 0; s >>= 1) mx = fmaxf(mx, __shfl_xor(mx, s, 64));
    float sum = 0.f; float e[7];
    #pragma unroll
    for (int i = 0; i < 7; ++i){
      int l = l32 + 32 * i;
      float ex = (l < 200) ? expf(vals[i] - mx) : 0.f;
      e[i] = ex; sum += ex;
    }
    #pragma unroll
    for (int s = 16; s > 0; s >>= 1) sum += __shfl_xor(sum, s, 64);
    float inv = 1.f / sum;
    #pragma unroll
    for (int i = 0; i < 7; ++i){
      int l = l32 + 32 * i;
      if (l < 200) s_alpha[l * 8 + head] = e[i] * inv;
    }
  }
  __syncthreads();

  // T[h] = sum_{l<len} alpha[l,h]
  if (t < 64){
    int h = t & 7, seg = t >> 3;
    int l0 = seg * 25, l1 = l0 + 25; if (l1 > len) l1 = len;
    float s = 0.f;
    for (int l = l0; l < l1; ++l) s += s_alpha[l * 8 + h];
    s_Tp[t] = s;
  }
  __syncthreads();
  if (t < 8){
    float s = 0.f;
    #pragma unroll
    for (int seg = 0; seg < 8; ++seg) s += s_Tp[seg * 8 + t];
    s_T[t] = s;
  }

  // phase d: re-gather rows, accumulate alpha-weighted head sums in registers
  float acc[64];
  #pragma unroll
  for (int e = 0; e < 64; ++e) acc[e] = 0.f;
  for (int l = gid; l < 200; l += 16){
    int it = s_it[l];
    if (it >= 0){
      float x[8];
      gather_norm8(emb, isf, it, p, x);
      float al[8];
      #pragma unroll
      for (int h = 0; h < 8; ++h) al[h] = s_alpha[l * 8 + h];
      #pragma unroll
      for (int h = 0; h < 8; ++h)
        #pragma unroll
        for (int e = 0; e < 8; ++e) acc[h * 8 + e] += al[h] * x[e];
    }
  }
  // reduce across the 4 groups within each wave
  #pragma unroll
  for (int e = 0; e < 64; ++e){
    float v = acc[e];
    v += __shfl_xor(v, 16, 64);
    v += __shfl_xor(v, 32, 64);
    acc[e] = v;
  }
  __syncthreads();   // region A: W1p dead, reuse as s_part
  if (lane < 16){
    #pragma unroll
    for (int h = 0; h < 8; ++h)
      #pragma unroll
      for (int e = 0; e < 8; ++e)
        s_part[wv * 1024 + h * 128 + p * 8 + e] = acc[h * 8 + e];
  }
  __syncthreads();
  for (int i = t; i < 1024; i += 256)
    s_part[i] = s_part[i] + s_part[1024 + i] + s_part[2048 + i] + s_part[3072 + i];
  __syncthreads();

  // phase e: a_raw = s_hl . W2T + T*b2 ; layernorm
  float araw = 0.f;
  if (t < 128){
    int head = t >> 4;
    araw = wts[C_B2 + t] * s_T[head];
    const float* hl = &s_part[head * 128];
    for (int k = 0; k < 128; ++k) araw += hl[k] * wts[C_W2T + k * 128 + t];
  }
  float v1 = wred(t < 128 ? araw : 0.f);
  if ((t & 63) == 0) s_red[t >> 6] = v1;
  __syncthreads();
  float mu = (s_red[0] + s_red[1]) * 0.0078125f;
  float dd = (t < 128) ? (araw - mu) : 0.f;
  float v2 = wred(dd * dd);
  if ((t & 63) == 0) s_red[4 + (t >> 6)] = v2;
  __syncthreads();
  float var = (s_red[4] + s_red[5]) * 0.0078125f;
  if (t < 128)
    s_a[t] = dd / sqrtf(var + 1e-8f) * wts[C_G + t] + wts[C_BB + t];
  __syncthreads();

  // phase f: out = normalize([a_ln | ht] . WtT + bt)
  float o = 0.f;
  if (t < 128){
    o = wts[C_BT + t];
    for (int k = 0; k < 128; ++k) o += s_a[k] * wts[C_WTT + k * 128 + t];
    for (int k = 0; k < 128; ++k) o += s_ht[k] * wts[C_WTT + (128 + k) * 128 + t];
  }
  float v3 = wred(t < 128 ? o * o : 0.f);
  if ((t & 63) == 0) s_red[8 + (t >> 6)] = v3;
  __syncthreads();
  float nrm = sqrtf(s_red[8] + s_red[9]);
  if (t < 128){
    float val = sane(o / (nrm + 1e-12f));
    if (isf) ((float*)outv)[b * 128 + t] = val;
    else     ((ushort*)outv)[b * 128 + t] = f2b(val);
  }
}

extern "C" void kernel_launch(void* const* d_in, const int* in_sizes, int n_in,
                              void* d_out, int out_size, void* d_ws, size_t ws_size,
                              hipStream_t stream){
  const int* alias_ = (const int*)d_in[0];
  const int* items  = (const int*)d_in[1];
  const int* mask   = (const int*)d_in[2];
  const void* emb = d_in[3];
  const void* W0  = d_in[4];
  const void* b0  = d_in[5];
  const void* W1  = d_in[6];
  const void* b1  = d_in[7];
  const void* W2  = d_in[8];
  const void* b2_ = d_in[9];
  const void* Wq  = d_in[10];
  const void* bq  = d_in[11];
  const void* Wt  = d_in[12];
  const void* bt  = d_in[13];
  const void* g_  = d_in[14];
  const void* bb_ = d_in[15];

  char* ws = (char*)d_ws;
  int*   ws_flag = (int*)ws;                  // 64 B
  float* wts     = (float*)(ws + 64);         // 396,800 B
  float* ws_ht   = (float*)(ws + 396864);     // 524,288 B
  float* ws_X0   = (float*)(ws + 921152);     // 524,288 B
  float* ws_c1   = (float*)(ws + 1445440);    // 262,144 B
  int*   ws_len  = (int*)(ws + 1707584);      // 4,096 B  (total ~1.71 MB)

  k_detect<<<dim3(1),    dim3(256), 0, stream>>>((const ushort*)emb, ws_flag);
  k_wts   <<<dim3(388),  dim3(256), 0, stream>>>(W0, b0, W1, b1, W2, b2_, Wq, bq,
                                                 Wt, bt, g_, bb_, ws_flag, wts);
  k_bout  <<<dim3(3125), dim3(256), 0, stream>>>(emb, ws_flag, d_out);
  k_prep  <<<dim3(1024), dim3(128), 0, stream>>>(alias_, items, mask, emb, wts, ws_flag,
                                                 ws_ht, ws_X0, ws_c1, ws_len);
  k_main  <<<dim3(1024), dim3(256), 0, stream>>>(alias_, items, mask, emb, wts,
                                                 ws_ht, ws_X0, ws_c1, ws_len, ws_flag, d_out);
}